// Round 5
// baseline (1005.261 us; speedup 1.0000x reference)
//
#include <hip/hip_runtime.h>
#include <hip/hip_bf16.h>
#include <hip/hip_cooperative_groups.h>

namespace cg = cooperative_groups;

// CSAA, round 5: single cooperative mega-kernel. Phase bodies identical to
// round 4 (verbatim math/layout/offsets), separated by grid.sync() instead of
// kernel boundaries. 512 blocks = 2/CU co-resident (LDS 67.5KB, VGPR<=256).
// Fallback to the round-4 multi-kernel path if cooperative launch fails.
//
// Phases:
//  W  : wprep (fp32 weights -> bf16 pre-swizzled images)         [sync]
//  P1 : rsz[b][p][h][w]   per (b,hw128)  B=x fp32 n-fast K=256   [sync]
//  P2 : q1,k1 + v1        per (b,p)/(b,u) B=rsz bf16 n-fast      [sync]
//  P3 : T1[b][p][o][w]    per (b,o) flash attn                   [sync]
//  P4 : q2,k2 + v2        per (b,c)/(b,u) B=T1 k-fast gload16    [sync]
//  P5 : T2[b][h][o2][c]   per (b,o2) flash attn, transp epilogue [sync]
//  P6 : out[b][co][h][o2] per (b,h)x2   fp32 out

typedef __attribute__((ext_vector_type(8))) short bf16x8;
typedef __attribute__((ext_vector_type(4))) float f32x4;

__device__ __forceinline__ short f2b(float f) {
    __hip_bfloat16 h = __float2bfloat16(f);
    short s; __builtin_memcpy(&s, &h, 2);
    return s;
}

__device__ __forceinline__ int swx(int row) { return (row ^ (row >> 3)) & 7; }
__device__ __forceinline__ int swzb(int row, int blk) {
    return (row << 7) + ((blk ^ swx(row)) << 3);
}

__device__ __forceinline__ void gload16(const void* g, void* l) {
    __builtin_amdgcn_global_load_lds(
        (const __attribute__((address_space(1))) void*)g,
        (__attribute__((address_space(3))) void*)l, 16, 0, 0);
}

__device__ __forceinline__ void mfma64(const short* __restrict__ SA,
                                       const short* __restrict__ SB,
                                       f32x4 (&acc)[4][4], int lane,
                                       int wr64, int wc64) {
    #pragma unroll
    for (int kk = 0; kk < 4; kk++) {
        const int kb = kk * 4 + (lane >> 4);
        bf16x8 a[4], b[4];
        #pragma unroll
        for (int mi = 0; mi < 4; mi++)
            a[mi] = *(const bf16x8*)&SA[swzb(wr64 + mi * 16 + (lane & 15), kb)];
        #pragma unroll
        for (int ni = 0; ni < 4; ni++)
            b[ni] = *(const bf16x8*)&SB[swzb(wc64 + ni * 16 + (lane & 15), kb)];
        #pragma unroll
        for (int mi = 0; mi < 4; mi++)
            #pragma unroll
            for (int ni = 0; ni < 4; ni++)
                acc[mi][ni] = __builtin_amdgcn_mfma_f32_16x16x32_bf16(
                    a[mi], b[ni], acc[mi][ni], 0, 0, 0);
    }
}

__device__ __forceinline__ void stage_nf_bf16(const short* __restrict__ Bb,
                                              long long b_r, int k0,
                                              short* __restrict__ Bs, int t) {
    const int n8 = t & 15, kb = t >> 4;
    bf16x8 rk[8];
    #pragma unroll
    for (int i = 0; i < 8; i++)
        rk[i] = *(const bf16x8*)(Bb + (long long)(k0 + kb * 8 + i) * b_r + n8 * 8);
    #pragma unroll
    for (int j = 0; j < 8; j++) {
        bf16x8 col;
        #pragma unroll
        for (int i = 0; i < 8; i++) col[i] = rk[i][j];
        *(bf16x8*)&Bs[swzb(n8 * 8 + j, kb)] = col;
    }
}

__device__ __forceinline__ void stage_nf_f32(const float* __restrict__ Bb,
                                             long long b_r, int k0,
                                             short* __restrict__ Bs, int t) {
    const int n8 = t & 15, kb = t >> 4;
    bf16x8 rk[8];
    #pragma unroll
    for (int i = 0; i < 8; i++) {
        const float* s = Bb + (long long)(k0 + kb * 8 + i) * b_r + n8 * 8;
        float4 v0 = *(const float4*)s, v1 = *(const float4*)(s + 4);
        rk[i][0] = f2b(v0.x); rk[i][1] = f2b(v0.y);
        rk[i][2] = f2b(v0.z); rk[i][3] = f2b(v0.w);
        rk[i][4] = f2b(v1.x); rk[i][5] = f2b(v1.y);
        rk[i][6] = f2b(v1.z); rk[i][7] = f2b(v1.w);
    }
    #pragma unroll
    for (int j = 0; j < 8; j++) {
        bf16x8 col;
        #pragma unroll
        for (int i = 0; i < 8; i++) col[i] = rk[i][j];
        *(bf16x8*)&Bs[swzb(n8 * 8 + j, kb)] = col;
    }
}

// ---------------- wprep body ----------------
__device__ __forceinline__ void wprep_body(
    int id, int g,
    const float* __restrict__ Wr, const float* __restrict__ Wqw,
    const float* __restrict__ Wkw, const float* __restrict__ Wvw,
    const float* __restrict__ Wqh, const float* __restrict__ Wkh,
    const float* __restrict__ Wvh, const float* __restrict__ Wo,
    short* __restrict__ dst) {
    const float* W; int M, K, off;
    switch (id) {
        case 0: W = Wr;  M = 128; K = 256; off = 0;      break;
        case 1: W = Wqw; M = 128; K = 128; off = 32768;  break;
        case 2: W = Wkw; M = 128; K = 128; off = 49152;  break;
        case 3: W = Wvw; M = 128; K = 128; off = 65536;  break;
        case 4: W = Wqh; M = 128; K = 128; off = 81920;  break;
        case 5: W = Wkh; M = 128; K = 128; off = 98304;  break;
        case 6: W = Wvh; M = 128; K = 128; off = 114688; break;
        default: W = Wo; M = 256; K = 128; off = 131072; break;
    }
    if (g >= (M * K) >> 3) return;
    int gpr = K >> 3;
    int row = g / gpr;
    int blk = g - row * gpr;
    int ks = blk >> 4, bi = blk & 15;
    int my = row >> 7, r = row & 127;
    int nks = K >> 7;
    const float* s = W + (long long)row * K + blk * 8;
    float4 v0 = *(const float4*)s, v1 = *(const float4*)(s + 4);
    bf16x8 ov;
    ov[0] = f2b(v0.x); ov[1] = f2b(v0.y); ov[2] = f2b(v0.z); ov[3] = f2b(v0.w);
    ov[4] = f2b(v1.x); ov[5] = f2b(v1.y); ov[6] = f2b(v1.z); ov[7] = f2b(v1.w);
    *(bf16x8*)(dst + off + (my * nks + ks) * 16384 + swzb(r, bi)) = ov;
}

// ---------------- GEMM job body ----------------
template<int NW, int KSTEPS, int BMODE, bool F32OUT>
__device__ __forceinline__ void gemm_job(
    int bx, int my, int bz,
    const short* __restrict__ A0, const short* __restrict__ A1,
    const float* __restrict__ bias0, const float* __restrict__ bias1,
    const void* __restrict__ Bsrc, long long b_z, long long b_x, long long b_r,
    short* __restrict__ C0, short* __restrict__ C1, float* __restrict__ Cf,
    long long c_z, long long c_x, long long c_m,
    short* __restrict__ As, short* __restrict__ Bs) {
    const int t = threadIdx.x;
    const int lane = t & 63;
    const int wid = t >> 6;
    const int wr64 = (wid >> 1) * 64, wc64 = (wid & 1) * 64;

    __syncthreads();   // LDS safe vs previous job

    f32x4 acc[NW][4][4];
    #pragma unroll
    for (int g = 0; g < NW; g++)
        #pragma unroll
        for (int mi = 0; mi < 4; mi++)
            #pragma unroll
            for (int ni = 0; ni < 4; ni++)
                acc[g][mi][ni] = (f32x4){0.f, 0.f, 0.f, 0.f};

    for (int ks = 0; ks < KSTEPS; ks++) {
        if (BMODE == 0) {
            const short* Bb = (const short*)Bsrc + bz * b_z + bx * b_x;
            #pragma unroll
            for (int i = 0; i < 8; i++) {
                int q = wid * 8 + i;
                int row = q * 4 + (lane >> 4);
                gload16(Bb + (long long)row * b_r + ks * 128
                           + (((lane & 15) ^ swx(row)) << 3), &Bs[q * 512]);
            }
        } else if (BMODE == 1) {
            stage_nf_bf16((const short*)Bsrc + bz * b_z + bx * b_x, b_r,
                          ks * 128, Bs, t);
        } else {
            stage_nf_f32((const float*)Bsrc + bz * b_z + bx * b_x, b_r,
                         ks * 128, Bs, t);
        }
        #pragma unroll
        for (int g = 0; g < NW; g++) {
            const short* Ai = ((g == 0) ? A0 : A1) + (my * KSTEPS + ks) * 16384;
            #pragma unroll
            for (int i = 0; i < 8; i++) {
                int q = wid * 8 + i;
                gload16(Ai + q * 512 + lane * 8, &As[q * 512]);
            }
            __syncthreads();
            mfma64(As, Bs, acc[g], lane, wr64, wc64);
            __syncthreads();
        }
    }

    if (F32OUT) {
        float* Cb = Cf + bz * c_z + bx * c_x;
        #pragma unroll
        for (int mi = 0; mi < 4; mi++)
            #pragma unroll
            for (int r = 0; r < 4; r++) {
                int rl = wr64 + mi * 16 + (lane >> 4) * 4 + r;
                int row = my * 128 + rl;
                float bb = bias0[row];
                #pragma unroll
                for (int ni = 0; ni < 4; ni++) {
                    int col = wc64 + ni * 16 + (lane & 15);
                    Cb[(long long)row * c_m + col] = acc[0][mi][ni][r] + bb;
                }
            }
    } else {
        #pragma unroll
        for (int g = 0; g < NW; g++) {
            const float* bias = (g == 0) ? bias0 : bias1;
            #pragma unroll
            for (int mi = 0; mi < 4; mi++)
                #pragma unroll
                for (int r = 0; r < 4; r++) {
                    int row = wr64 + mi * 16 + (lane >> 4) * 4 + r;
                    float bb = bias[row];
                    #pragma unroll
                    for (int ni = 0; ni < 4; ni++) {
                        int col = wc64 + ni * 16 + (lane & 15);
                        As[swzb(row, col >> 3) + (col & 7)] = f2b(acc[g][mi][ni][r] + bb);
                    }
                }
            __syncthreads();
            short* Cg = ((g == 0) ? C0 : C1) + bz * c_z + bx * c_x;
            #pragma unroll
            for (int i = 0; i < 8; i++) {
                int idx = t + i * 256;
                int row = idx >> 4, ch = idx & 15;
                *(bf16x8*)(Cg + (long long)row * c_m + ch * 8) =
                    *(const bf16x8*)&As[swzb(row, ch)];
            }
            __syncthreads();
        }
    }
}

// ---------------- attention job body ----------------
template<bool TEPI>
__device__ __forceinline__ void attn_job(
    int bx, int bz,
    const short* __restrict__ Q, const short* __restrict__ Kp,
    const short* __restrict__ V, short* __restrict__ O,
    short* __restrict__ SA, short* __restrict__ SB,
    float (*pmax)[128], float (*psum)[128]) {
    const int t = threadIdx.x;
    const int lane = t & 63;
    const int wid = t >> 6;
    const int wr64 = (wid >> 1) * 64, wc64 = (wid & 1) * 64, wch = wid & 1;
    const long long poff = (long long)bz * 2097152LL + (long long)bx * 16384LL;
    const short* Qb = Q + poff;
    const short* Kb = Kp + poff;
    const short* Vb = V + poff;
    short* Ob = O + (long long)bz * 2097152LL + (long long)bx * 128LL;

    __syncthreads();   // LDS safe vs previous job

    #pragma unroll
    for (int i = 0; i < 8; i++) {
        int q = wid * 8 + i;
        int row = q * 4 + (lane >> 4);
        int sw = (((lane & 15) ^ swx(row)) << 3);
        gload16(Qb + row * 128 + sw, &SA[q * 512]);
        gload16(Kb + row * 128 + sw, &SB[q * 512]);
    }
    __syncthreads();

    f32x4 acc[4][4];
    #pragma unroll
    for (int mi = 0; mi < 4; mi++)
        #pragma unroll
        for (int ni = 0; ni < 4; ni++) acc[mi][ni] = (f32x4){0.f, 0.f, 0.f, 0.f};
    mfma64(SA, SB, acc, lane, wr64, wc64);

    #pragma unroll
    for (int mi = 0; mi < 4; mi++)
        #pragma unroll
        for (int r = 0; r < 4; r++) {
            float mx = fmaxf(fmaxf(acc[mi][0][r], acc[mi][1][r]),
                             fmaxf(acc[mi][2][r], acc[mi][3][r]));
            #pragma unroll
            for (int d = 1; d < 16; d <<= 1) mx = fmaxf(mx, __shfl_xor(mx, d, 64));
            if ((lane & 15) == 0)
                pmax[wch][wr64 + mi * 16 + (lane >> 4) * 4 + r] = mx;
        }
    __syncthreads();   // bar1

    const int n8 = t & 15, kb = t >> 4;
    bf16x8 vk[8];
    #pragma unroll
    for (int i = 0; i < 8; i++)
        vk[i] = *(const bf16x8*)(Vb + (kb * 8 + i) * 128 + n8 * 8);

    #pragma unroll
    for (int mi = 0; mi < 4; mi++)
        #pragma unroll
        for (int r = 0; r < 4; r++) {
            int row = wr64 + mi * 16 + (lane >> 4) * 4 + r;
            float M = fmaxf(pmax[0][row], pmax[1][row]);
            float p[4], s = 0.f;
            #pragma unroll
            for (int ni = 0; ni < 4; ni++) {
                p[ni] = __expf(acc[mi][ni][r] - M);
                s += p[ni];
            }
            #pragma unroll
            for (int d = 1; d < 16; d <<= 1) s += __shfl_xor(s, d, 64);
            if ((lane & 15) == 0) psum[wch][row] = s;
            #pragma unroll
            for (int ni = 0; ni < 4; ni++) {
                int col = wc64 + ni * 16 + (lane & 15);
                SA[swzb(row, col >> 3) + (col & 7)] = f2b(p[ni]);
            }
        }
    #pragma unroll
    for (int j = 0; j < 8; j++) {
        bf16x8 col;
        #pragma unroll
        for (int i = 0; i < 8; i++) col[i] = vk[i][j];
        *(bf16x8*)&SB[swzb(n8 * 8 + j, kb)] = col;
    }
    __syncthreads();   // bar2

    f32x4 acc2[4][4];
    #pragma unroll
    for (int mi = 0; mi < 4; mi++)
        #pragma unroll
        for (int ni = 0; ni < 4; ni++) acc2[mi][ni] = (f32x4){0.f, 0.f, 0.f, 0.f};
    mfma64(SA, SB, acc2, lane, wr64, wc64);
    __syncthreads();   // bar3

    #pragma unroll
    for (int mi = 0; mi < 4; mi++)
        #pragma unroll
        for (int r = 0; r < 4; r++) {
            int row = wr64 + mi * 16 + (lane >> 4) * 4 + r;
            float rinv = 1.f / (psum[0][row] + psum[1][row]);
            #pragma unroll
            for (int ni = 0; ni < 4; ni++) {
                int col = wc64 + ni * 16 + (lane & 15);
                short vv = f2b(acc2[mi][ni][r] * rinv);
                if (!TEPI) SB[swzb(row, col >> 3) + (col & 7)] = vv;
                else       SB[swzb(col, row >> 3) + (row & 7)] = vv;
            }
        }
    __syncthreads();
    #pragma unroll
    for (int i = 0; i < 8; i++) {
        int idx = t + i * 256;
        int row = idx >> 4, ch = idx & 15;
        *(bf16x8*)(Ob + (long long)row * 16384 + ch * 8) =
            *(const bf16x8*)&SB[swzb(row, ch)];
    }
}

// ---------------- cooperative mega-kernel ----------------
__global__ __launch_bounds__(256, 2)
void csaa_coop(const float* x,
               const float* Wr, const float* br,
               const float* Wqw, const float* bqw,
               const float* Wkw, const float* bkw,
               const float* Wvw, const float* bvw,
               const float* Wqh, const float* bqh,
               const float* Wkh, const float* bkh,
               const float* Wvh, const float* bvh,
               const float* Wo, const float* bo,
               float* out, short* wsp) {
    __shared__ short SA[16384];
    __shared__ short SB[16384];
    __shared__ float pmax[2][128];
    __shared__ float psum[2][128];

    const long long U = 16777216LL;
    short* s0 = wsp;
    short* s1 = wsp + U;
    short* s2 = wsp + 2 * U;
    short* s3 = wsp + 3 * U;
    short* wb = wsp + 4 * U;
    short* wWr  = wb;
    short* wWqw = wb + 32768;
    short* wWkw = wb + 49152;
    short* wWvw = wb + 65536;
    short* wWqh = wb + 81920;
    short* wWkh = wb + 98304;
    short* wWvh = wb + 114688;
    short* wWo  = wb + 131072;

    cg::grid_group grid = cg::this_grid();
    const int bid = blockIdx.x;

    // ---- W: weight prep ----
    {
        int F = bid * 256 + (int)threadIdx.x;
        int id = F >> 12;
        if (id < 8)
            wprep_body(id, F & 4095, Wr, Wqw, Wkw, Wvw, Wqh, Wkh, Wvh, Wo, wb);
    }
    __threadfence(); grid.sync();

    // ---- P1: rsz <- x ----
    for (int j = bid; j < 1024; j += 512)
        gemm_job<1, 2, 2, false>(j & 127, 0, j >> 7,
            wWr, nullptr, br, nullptr,
            x, 4194304LL, 128LL, 16384LL,
            s0, nullptr, nullptr, 2097152LL, 128LL, 16384LL, SA, SB);
    __threadfence(); grid.sync();

    // ---- P2: q1,k1 then v1 ----
    for (int j = bid; j < 1024; j += 512)
        gemm_job<2, 1, 1, false>(j & 127, 0, j >> 7,
            wWqw, wWkw, bqw, bkw,
            s0, 2097152LL, 16384LL, 128LL,
            s1, s2, nullptr, 2097152LL, 128LL, 16384LL, SA, SB);
    for (int j = bid; j < 1024; j += 512)
        gemm_job<1, 1, 1, false>(j & 127, 0, j >> 7,
            wWvw, nullptr, bvw, nullptr,
            s0, 2097152LL, 16384LL, 128LL,
            s3, nullptr, nullptr, 2097152LL, 128LL, 16384LL, SA, SB);
    __threadfence(); grid.sync();

    // ---- P3: width attention -> T1 (s0) ----
    for (int j = bid; j < 1024; j += 512)
        attn_job<false>(j & 127, j >> 7, s1, s2, s3, s0, SA, SB, pmax, psum);
    __threadfence(); grid.sync();

    // ---- P4: q2,k2 then v2 ----
    for (int j = bid; j < 1024; j += 512)
        gemm_job<2, 1, 0, false>(j & 127, 0, j >> 7,
            wWqh, wWkh, bqh, bkh,
            s0, 2097152LL, 16384LL, 128LL,
            s1, s2, nullptr, 2097152LL, 128LL, 16384LL, SA, SB);
    for (int j = bid; j < 1024; j += 512)
        gemm_job<1, 1, 0, false>(j & 127, 0, j >> 7,
            wWvh, nullptr, bvh, nullptr,
            s0, 2097152LL, 16384LL, 128LL,
            s3, nullptr, nullptr, 2097152LL, 128LL, 16384LL, SA, SB);
    __threadfence(); grid.sync();

    // ---- P5: height attention -> T2 (s0) ----
    for (int j = bid; j < 1024; j += 512)
        attn_job<true>(j & 127, j >> 7, s1, s2, s3, s0, SA, SB, pmax, psum);
    __threadfence(); grid.sync();

    // ---- P6: restore -> out (fp32) ----
    for (int j = bid; j < 2048; j += 512)
        gemm_job<1, 1, 0, true>(j & 127, (j >> 7) & 1, j >> 8,
            wWo, nullptr, bo, nullptr,
            s0, 2097152LL, 16384LL, 128LL,
            nullptr, nullptr, out, 4194304LL, 128LL, 16384LL, SA, SB);
}

// ---------------- standalone fallback kernels (round-4 path) ----------------
__global__ __launch_bounds__(256)
void wprep(const float* __restrict__ Wr, const float* __restrict__ Wqw,
           const float* __restrict__ Wkw, const float* __restrict__ Wvw,
           const float* __restrict__ Wqh, const float* __restrict__ Wkh,
           const float* __restrict__ Wvh, const float* __restrict__ Wo,
           short* __restrict__ dst) {
    wprep_body(blockIdx.y, blockIdx.x * 256 + threadIdx.x,
               Wr, Wqw, Wkw, Wvw, Wqh, Wkh, Wvh, Wo, dst);
}

template<int NW, int KSTEPS, int BMODE, bool F32OUT>
__global__ __launch_bounds__(256)
void gemmw(const short* A0, const short* A1,
           const float* bias0, const float* bias1,
           const void* Bsrc, long long b_z, long long b_x, long long b_r,
           short* C0, short* C1, float* Cf,
           long long c_z, long long c_x, long long c_m) {
    __shared__ short As[16384];
    __shared__ short Bs[16384];
    gemm_job<NW, KSTEPS, BMODE, F32OUT>(blockIdx.x, blockIdx.y, blockIdx.z,
        A0, A1, bias0, bias1, Bsrc, b_z, b_x, b_r,
        C0, C1, Cf, c_z, c_x, c_m, As, Bs);
}

template<bool TEPI>
__global__ __launch_bounds__(256)
void attnk(const short* Q, const short* Kp, const short* V, short* O) {
    __shared__ short SA[16384];
    __shared__ short SB[16384];
    __shared__ float pmax[2][128];
    __shared__ float psum[2][128];
    attn_job<TEPI>(blockIdx.x, blockIdx.z, Q, Kp, V, O, SA, SB, pmax, psum);
}

extern "C" void kernel_launch(void* const* d_in, const int* in_sizes, int n_in,
                              void* d_out, int out_size, void* d_ws, size_t ws_size,
                              hipStream_t stream) {
    const float* x   = (const float*)d_in[0];
    const float* Wr  = (const float*)d_in[1];
    const float* br  = (const float*)d_in[2];
    const float* Wqw = (const float*)d_in[3];
    const float* bqw = (const float*)d_in[4];
    const float* Wkw = (const float*)d_in[5];
    const float* bkw = (const float*)d_in[6];
    const float* Wvw = (const float*)d_in[7];
    const float* bvw = (const float*)d_in[8];
    const float* Wqh = (const float*)d_in[9];
    const float* bqh = (const float*)d_in[10];
    const float* Wkh = (const float*)d_in[11];
    const float* bkh = (const float*)d_in[12];
    const float* Wvh = (const float*)d_in[13];
    const float* bvh = (const float*)d_in[14];
    const float* Wo  = (const float*)d_in[15];
    const float* bo  = (const float*)d_in[16];
    float* out = (float*)d_out;
    short* wsp = (short*)d_ws;
    (void)in_sizes; (void)n_in; (void)out_size; (void)ws_size;

    // ---- preferred: one cooperative launch ----
    {
        void* args[19] = {
            (void*)&x,
            (void*)&Wr, (void*)&br, (void*)&Wqw, (void*)&bqw,
            (void*)&Wkw, (void*)&bkw, (void*)&Wvw, (void*)&bvw,
            (void*)&Wqh, (void*)&bqh, (void*)&Wkh, (void*)&bkh,
            (void*)&Wvh, (void*)&bvh, (void*)&Wo, (void*)&bo,
            (void*)&out, (void*)&wsp
        };
        hipError_t err = hipLaunchCooperativeKernel(
            (void*)csaa_coop, dim3(512), dim3(256), args, 0, stream);
        if (err == hipSuccess) return;
    }

    // ---- fallback: round-4 multi-kernel path ----
    const long long U = 16777216LL;
    short* s0 = wsp;
    short* s1 = wsp + U;
    short* s2 = wsp + 2 * U;
    short* s3 = wsp + 3 * U;
    short* wb = wsp + 4 * U;
    short* wWr  = wb;
    short* wWqw = wb + 32768;
    short* wWkw = wb + 49152;
    short* wWvw = wb + 65536;
    short* wWqh = wb + 81920;
    short* wWkh = wb + 98304;
    short* wWvh = wb + 114688;
    short* wWo  = wb + 131072;

    dim3 blk(256);
    wprep<<<dim3(16, 8), blk, 0, stream>>>(Wr, Wqw, Wkw, Wvw, Wqh, Wkh, Wvh, Wo, wb);
    gemmw<1, 2, 2, false><<<dim3(128, 1, 8), blk, 0, stream>>>(
        wWr, nullptr, br, nullptr, x, 4194304LL, 128LL, 16384LL,
        s0, nullptr, nullptr, 2097152LL, 128LL, 16384LL);
    gemmw<2, 1, 1, false><<<dim3(128, 1, 8), blk, 0, stream>>>(
        wWqw, wWkw, bqw, bkw, s0, 2097152LL, 16384LL, 128LL,
        s1, s2, nullptr, 2097152LL, 128LL, 16384LL);
    gemmw<1, 1, 1, false><<<dim3(128, 1, 8), blk, 0, stream>>>(
        wWvw, nullptr, bvw, nullptr, s0, 2097152LL, 16384LL, 128LL,
        s3, nullptr, nullptr, 2097152LL, 128LL, 16384LL);
    attnk<false><<<dim3(128, 1, 8), blk, 0, stream>>>(s1, s2, s3, s0);
    gemmw<2, 1, 0, false><<<dim3(128, 1, 8), blk, 0, stream>>>(
        wWqh, wWkh, bqh, bkh, s0, 2097152LL, 16384LL, 128LL,
        s1, s2, nullptr, 2097152LL, 128LL, 16384LL);
    gemmw<1, 1, 0, false><<<dim3(128, 1, 8), blk, 0, stream>>>(
        wWvh, nullptr, bvh, nullptr, s0, 2097152LL, 16384LL, 128LL,
        s3, nullptr, nullptr, 2097152LL, 128LL, 16384LL);
    attnk<true><<<dim3(128, 1, 8), blk, 0, stream>>>(s1, s2, s3, s0);
    gemmw<1, 1, 0, true><<<dim3(128, 2, 8), blk, 0, stream>>>(
        wWo, nullptr, bo, nullptr, s0, 2097152LL, 16384LL, 128LL,
        nullptr, nullptr, out, 4194304LL, 128LL, 16384LL);
}

// Round 6
// 392.588 us; speedup vs baseline: 2.5606x; 2.5606x over previous
//
#include <hip/hip_runtime.h>
#include <hip/hip_bf16.h>

// CSAA, round 6: back to multi-kernel (round-4 graph), occupancy-first GEMM.
//  - Weight images in FRAGMENT-LINEAR layout -> A-fragments loaded straight
//    from global (L2-hot), no A LDS panel. GEMM LDS = 32KB (B only).
//  - Epilogue: direct scalar bf16/f32 stores from fragments (no LDS bounce,
//    no barriers). Intermediates are L3-resident; L2 merges the 32B segments.
//  - __launch_bounds__(256,4): VGPR<=128 -> 4 blocks/CU on GEMM kernels.
//  - P2 (q1,k1,v1) and P4 (q2,k2,v2) fused as NW=3 sequential-g kernels
//    sharing one staged B panel.
// Pass graph (strides verbatim from round 4):
//  P1 : rsz[b][p][h][w]    per (b,hw128) B=x fp32 n-fast, K=256
//  P2 : q1,k1,v1           per (b,p)     B=rsz bf16 n-fast (NW=3)
//  P3 : T1[b][p][o][w]     per (b,o)     flash attn
//  P4 : q2,k2,v2           per (b,c)     B=T1 k-fast gload16 (NW=3)
//  P5 : T2[b][h][o2][c]    per (b,o2)    flash attn, transposed epilogue
//  P6 : out[b][co][h][o2]  per (b,h)x2   fp32 out

typedef __attribute__((ext_vector_type(8))) short bf16x8;
typedef __attribute__((ext_vector_type(4))) float f32x4;

__device__ __forceinline__ short f2b(float f) {
    __hip_bfloat16 h = __float2bfloat16(f);
    short s; __builtin_memcpy(&s, &h, 2);
    return s;
}

__device__ __forceinline__ int swx(int row) { return (row ^ (row >> 3)) & 7; }
__device__ __forceinline__ int swzb(int row, int blk) {
    return (row << 7) + ((blk ^ swx(row)) << 3);
}

__device__ __forceinline__ void gload16(const void* g, void* l) {
    __builtin_amdgcn_global_load_lds(
        (const __attribute__((address_space(1))) void*)g,
        (__attribute__((address_space(3))) void*)l, 16, 0, 0);
}

// A from global fragment-linear image, B from swizzled LDS.
__device__ __forceinline__ void mfma_gab(const short* __restrict__ Ai,
                                         const short* __restrict__ Bs,
                                         f32x4 (&acc)[4][4], int lane,
                                         int wr64, int wc64) {
    #pragma unroll
    for (int kk = 0; kk < 4; kk++) {
        const int kb = kk * 4 + (lane >> 4);
        bf16x8 a[4], b[4];
        #pragma unroll
        for (int mi = 0; mi < 4; mi++)
            a[mi] = *(const bf16x8*)(Ai + kb * 1024
                                        + (wr64 + mi * 16 + (lane & 15)) * 8);
        #pragma unroll
        for (int ni = 0; ni < 4; ni++)
            b[ni] = *(const bf16x8*)&Bs[swzb(wc64 + ni * 16 + (lane & 15), kb)];
        #pragma unroll
        for (int mi = 0; mi < 4; mi++)
            #pragma unroll
            for (int ni = 0; ni < 4; ni++)
                acc[mi][ni] = __builtin_amdgcn_mfma_f32_16x16x32_bf16(
                    a[mi], b[ni], acc[mi][ni], 0, 0, 0);
    }
}

// A and B both from swizzled LDS (attention).
__device__ __forceinline__ void mfma64(const short* __restrict__ SA,
                                       const short* __restrict__ SB,
                                       f32x4 (&acc)[4][4], int lane,
                                       int wr64, int wc64) {
    #pragma unroll
    for (int kk = 0; kk < 4; kk++) {
        const int kb = kk * 4 + (lane >> 4);
        bf16x8 a[4], b[4];
        #pragma unroll
        for (int mi = 0; mi < 4; mi++)
            a[mi] = *(const bf16x8*)&SA[swzb(wr64 + mi * 16 + (lane & 15), kb)];
        #pragma unroll
        for (int ni = 0; ni < 4; ni++)
            b[ni] = *(const bf16x8*)&SB[swzb(wc64 + ni * 16 + (lane & 15), kb)];
        #pragma unroll
        for (int mi = 0; mi < 4; mi++)
            #pragma unroll
            for (int ni = 0; ni < 4; ni++)
                acc[mi][ni] = __builtin_amdgcn_mfma_f32_16x16x32_bf16(
                    a[mi], b[ni], acc[mi][ni], 0, 0, 0);
    }
}

__device__ __forceinline__ void stage_nf_bf16(const short* __restrict__ Bb,
                                              long long b_r, int k0,
                                              short* __restrict__ Bs, int t) {
    const int n8 = t & 15, kb = t >> 4;
    bf16x8 rk[8];
    #pragma unroll
    for (int i = 0; i < 8; i++)
        rk[i] = *(const bf16x8*)(Bb + (long long)(k0 + kb * 8 + i) * b_r + n8 * 8);
    #pragma unroll
    for (int j = 0; j < 8; j++) {
        bf16x8 col;
        #pragma unroll
        for (int i = 0; i < 8; i++) col[i] = rk[i][j];
        *(bf16x8*)&Bs[swzb(n8 * 8 + j, kb)] = col;
    }
}

__device__ __forceinline__ void stage_nf_f32(const float* __restrict__ Bb,
                                             long long b_r, int k0,
                                             short* __restrict__ Bs, int t) {
    const int n8 = t & 15, kb = t >> 4;
    bf16x8 rk[8];
    #pragma unroll
    for (int i = 0; i < 8; i++) {
        const float* s = Bb + (long long)(k0 + kb * 8 + i) * b_r + n8 * 8;
        float4 v0 = *(const float4*)s, v1 = *(const float4*)(s + 4);
        rk[i][0] = f2b(v0.x); rk[i][1] = f2b(v0.y);
        rk[i][2] = f2b(v0.z); rk[i][3] = f2b(v0.w);
        rk[i][4] = f2b(v1.x); rk[i][5] = f2b(v1.y);
        rk[i][6] = f2b(v1.z); rk[i][7] = f2b(v1.w);
    }
    #pragma unroll
    for (int j = 0; j < 8; j++) {
        bf16x8 col;
        #pragma unroll
        for (int i = 0; i < 8; i++) col[i] = rk[i][j];
        *(bf16x8*)&Bs[swzb(n8 * 8 + j, kb)] = col;
    }
}

// ---------------- wprep: fp32 weights -> bf16 FRAGMENT-LINEAR images -------
// Image element (my,ks,kb,row,e) at off + ((my*nks+ks)*16 + kb)*1024 + row*8+e
// holds W[my*128+row][ks*128 + kb*8 + e]. A-fragment loads become 256B-
// contiguous global reads.
__global__ __launch_bounds__(256)
void wprep(const float* __restrict__ Wr, const float* __restrict__ Wqw,
           const float* __restrict__ Wkw, const float* __restrict__ Wvw,
           const float* __restrict__ Wqh, const float* __restrict__ Wkh,
           const float* __restrict__ Wvh, const float* __restrict__ Wo,
           short* __restrict__ dst) {
    const int id = blockIdx.y;
    const float* W; int M, K, off;
    switch (id) {
        case 0: W = Wr;  M = 128; K = 256; off = 0;      break;
        case 1: W = Wqw; M = 128; K = 128; off = 32768;  break;
        case 2: W = Wkw; M = 128; K = 128; off = 49152;  break;
        case 3: W = Wvw; M = 128; K = 128; off = 65536;  break;
        case 4: W = Wqh; M = 128; K = 128; off = 81920;  break;
        case 5: W = Wkh; M = 128; K = 128; off = 98304;  break;
        case 6: W = Wvh; M = 128; K = 128; off = 114688; break;
        default: W = Wo; M = 256; K = 128; off = 131072; break;
    }
    int g = blockIdx.x * 256 + threadIdx.x;
    if (g >= (M * K) >> 3) return;
    int gpr = K >> 3;
    int row = g / gpr;
    int blk = g - row * gpr;
    int ks = blk >> 4, kb = blk & 15;
    int my = row >> 7, r = row & 127;
    int nks = K >> 7;
    const float* s = W + (long long)row * K + blk * 8;
    float4 v0 = *(const float4*)s, v1 = *(const float4*)(s + 4);
    bf16x8 ov;
    ov[0] = f2b(v0.x); ov[1] = f2b(v0.y); ov[2] = f2b(v0.z); ov[3] = f2b(v0.w);
    ov[4] = f2b(v1.x); ov[5] = f2b(v1.y); ov[6] = f2b(v1.z); ov[7] = f2b(v1.w);
    *(bf16x8*)(dst + off + ((my * nks + ks) * 16 + kb) * 1024 + r * 8) = ov;
}

// ---------------- weight-GEMM, B-only LDS, direct-store epilogue -----------
// BMODE: 0 = B k-fast (gload16), 1 = B n-fast bf16, 2 = B n-fast fp32.
// NW>1 requires KSTEPS==1 (g-loop reuses the staged B panel).
template<int NW, int KSTEPS, int BMODE, bool F32OUT>
__global__ __launch_bounds__(256, 4)
void gemmw(const short* __restrict__ A0, const short* __restrict__ A1,
           const short* __restrict__ A2,
           const float* __restrict__ bias0, const float* __restrict__ bias1,
           const float* __restrict__ bias2,
           const void* __restrict__ Bsrc, long long b_z, long long b_x, long long b_r,
           short* __restrict__ C0, short* __restrict__ C1, short* __restrict__ C2,
           float* __restrict__ Cf,
           long long c_z, long long c_x, long long c_m) {
    __shared__ short Bs[16384];
    const int t = threadIdx.x;
    const int lane = t & 63;
    const int wid = t >> 6;
    const int wr64 = (wid >> 1) * 64, wc64 = (wid & 1) * 64;
    const int bx = blockIdx.x, my = blockIdx.y, bz = blockIdx.z;

    if (KSTEPS == 1) {
        // stage B once
        if (BMODE == 0) {
            const short* Bb = (const short*)Bsrc + bz * b_z + bx * b_x;
            #pragma unroll
            for (int i = 0; i < 8; i++) {
                int q = wid * 8 + i;
                int row = q * 4 + (lane >> 4);
                gload16(Bb + (long long)row * b_r
                           + (((lane & 15) ^ swx(row)) << 3), &Bs[q * 512]);
            }
        } else if (BMODE == 1) {
            stage_nf_bf16((const short*)Bsrc + bz * b_z + bx * b_x, b_r, 0, Bs, t);
        } else {
            stage_nf_f32((const float*)Bsrc + bz * b_z + bx * b_x, b_r, 0, Bs, t);
        }
        __syncthreads();

        #pragma unroll
        for (int g = 0; g < NW; g++) {
            const short* Ai = ((g == 0) ? A0 : (g == 1) ? A1 : A2) + my * 16384;
            const float* bias = (g == 0) ? bias0 : (g == 1) ? bias1 : bias2;
            f32x4 acc[4][4];
            #pragma unroll
            for (int mi = 0; mi < 4; mi++)
                #pragma unroll
                for (int ni = 0; ni < 4; ni++)
                    acc[mi][ni] = (f32x4){0.f, 0.f, 0.f, 0.f};
            mfma_gab(Ai, Bs, acc, lane, wr64, wc64);

            if (F32OUT) {
                float* Cb = Cf + bz * c_z + bx * c_x;
                #pragma unroll
                for (int mi = 0; mi < 4; mi++)
                    #pragma unroll
                    for (int r = 0; r < 4; r++) {
                        int row = my * 128 + wr64 + mi * 16 + (lane >> 4) * 4 + r;
                        float bb = bias[row];
                        float* cp = Cb + (long long)row * c_m + wc64 + (lane & 15);
                        #pragma unroll
                        for (int ni = 0; ni < 4; ni++)
                            cp[ni * 16] = acc[mi][ni][r] + bb;
                    }
            } else {
                short* Cg = ((g == 0) ? C0 : (g == 1) ? C1 : C2)
                          + bz * c_z + bx * c_x;
                #pragma unroll
                for (int mi = 0; mi < 4; mi++)
                    #pragma unroll
                    for (int r = 0; r < 4; r++) {
                        int row = wr64 + mi * 16 + (lane >> 4) * 4 + r;
                        float bb = bias[row];
                        short* cp = Cg + (long long)row * c_m + wc64 + (lane & 15);
                        #pragma unroll
                        for (int ni = 0; ni < 4; ni++)
                            cp[ni * 16] = f2b(acc[mi][ni][r] + bb);
                    }
            }
        }
    } else {
        // NW==1, multi-kstep (P1)
        f32x4 acc[4][4];
        #pragma unroll
        for (int mi = 0; mi < 4; mi++)
            #pragma unroll
            for (int ni = 0; ni < 4; ni++)
                acc[mi][ni] = (f32x4){0.f, 0.f, 0.f, 0.f};
        for (int ks = 0; ks < KSTEPS; ks++) {
            if (ks) __syncthreads();   // protect Bs from restage
            if (BMODE == 0) {
                const short* Bb = (const short*)Bsrc + bz * b_z + bx * b_x;
                #pragma unroll
                for (int i = 0; i < 8; i++) {
                    int q = wid * 8 + i;
                    int row = q * 4 + (lane >> 4);
                    gload16(Bb + (long long)row * b_r + ks * 128
                               + (((lane & 15) ^ swx(row)) << 3), &Bs[q * 512]);
                }
            } else if (BMODE == 1) {
                stage_nf_bf16((const short*)Bsrc + bz * b_z + bx * b_x, b_r,
                              ks * 128, Bs, t);
            } else {
                stage_nf_f32((const float*)Bsrc + bz * b_z + bx * b_x, b_r,
                             ks * 128, Bs, t);
            }
            __syncthreads();
            mfma_gab(A0 + (my * KSTEPS + ks) * 16384, Bs, acc, lane, wr64, wc64);
        }
        if (F32OUT) {
            float* Cb = Cf + bz * c_z + bx * c_x;
            #pragma unroll
            for (int mi = 0; mi < 4; mi++)
                #pragma unroll
                for (int r = 0; r < 4; r++) {
                    int row = my * 128 + wr64 + mi * 16 + (lane >> 4) * 4 + r;
                    float bb = bias0[row];
                    float* cp = Cb + (long long)row * c_m + wc64 + (lane & 15);
                    #pragma unroll
                    for (int ni = 0; ni < 4; ni++)
                        cp[ni * 16] = acc[mi][ni][r] + bb;
                }
        } else {
            short* Cg = C0 + bz * c_z + bx * c_x;
            #pragma unroll
            for (int mi = 0; mi < 4; mi++)
                #pragma unroll
                for (int r = 0; r < 4; r++) {
                    int row = wr64 + mi * 16 + (lane >> 4) * 4 + r;
                    float bb = bias0[row];
                    short* cp = Cg + (long long)row * c_m + wc64 + (lane & 15);
                    #pragma unroll
                    for (int ni = 0; ni < 4; ni++)
                        cp[ni * 16] = f2b(acc[mi][ni][r] + bb);
                }
        }
    }
}

// ---------------- fused attention per (b,o) (round-4 verbatim) -------------
template<bool TEPI>
__global__ __launch_bounds__(256)
void attnk(const short* __restrict__ Q, const short* __restrict__ Kp,
           const short* __restrict__ V, short* __restrict__ O) {
    __shared__ short SA[16384];
    __shared__ short SB[16384];
    __shared__ float pmax[2][128];
    __shared__ float psum[2][128];
    const int t = threadIdx.x;
    const int lane = t & 63;
    const int wid = t >> 6;
    const int wr64 = (wid >> 1) * 64, wc64 = (wid & 1) * 64, wch = wid & 1;
    const long long poff = (long long)blockIdx.z * 2097152LL
                         + (long long)blockIdx.x * 16384LL;
    const short* Qb = Q + poff;
    const short* Kb = Kp + poff;
    const short* Vb = V + poff;
    short* Ob = O + (long long)blockIdx.z * 2097152LL + (long long)blockIdx.x * 128LL;

    #pragma unroll
    for (int i = 0; i < 8; i++) {
        int q = wid * 8 + i;
        int row = q * 4 + (lane >> 4);
        int sw = (((lane & 15) ^ swx(row)) << 3);
        gload16(Qb + row * 128 + sw, &SA[q * 512]);
        gload16(Kb + row * 128 + sw, &SB[q * 512]);
    }
    __syncthreads();

    f32x4 acc[4][4];
    #pragma unroll
    for (int mi = 0; mi < 4; mi++)
        #pragma unroll
        for (int ni = 0; ni < 4; ni++) acc[mi][ni] = (f32x4){0.f, 0.f, 0.f, 0.f};
    mfma64(SA, SB, acc, lane, wr64, wc64);

    #pragma unroll
    for (int mi = 0; mi < 4; mi++)
        #pragma unroll
        for (int r = 0; r < 4; r++) {
            float mx = fmaxf(fmaxf(acc[mi][0][r], acc[mi][1][r]),
                             fmaxf(acc[mi][2][r], acc[mi][3][r]));
            #pragma unroll
            for (int d = 1; d < 16; d <<= 1) mx = fmaxf(mx, __shfl_xor(mx, d, 64));
            if ((lane & 15) == 0)
                pmax[wch][wr64 + mi * 16 + (lane >> 4) * 4 + r] = mx;
        }
    __syncthreads();   // bar1: maxes visible; SA/SB reads complete

    const int n8 = t & 15, kb = t >> 4;
    bf16x8 vk[8];
    #pragma unroll
    for (int i = 0; i < 8; i++)
        vk[i] = *(const bf16x8*)(Vb + (kb * 8 + i) * 128 + n8 * 8);

    #pragma unroll
    for (int mi = 0; mi < 4; mi++)
        #pragma unroll
        for (int r = 0; r < 4; r++) {
            int row = wr64 + mi * 16 + (lane >> 4) * 4 + r;
            float M = fmaxf(pmax[0][row], pmax[1][row]);
            float p[4], s = 0.f;
            #pragma unroll
            for (int ni = 0; ni < 4; ni++) {
                p[ni] = __expf(acc[mi][ni][r] - M);
                s += p[ni];
            }
            #pragma unroll
            for (int d = 1; d < 16; d <<= 1) s += __shfl_xor(s, d, 64);
            if ((lane & 15) == 0) psum[wch][row] = s;
            #pragma unroll
            for (int ni = 0; ni < 4; ni++) {
                int col = wc64 + ni * 16 + (lane & 15);
                SA[swzb(row, col >> 3) + (col & 7)] = f2b(p[ni]);
            }
        }
    #pragma unroll
    for (int j = 0; j < 8; j++) {
        bf16x8 col;
        #pragma unroll
        for (int i = 0; i < 8; i++) col[i] = vk[i][j];
        *(bf16x8*)&SB[swzb(n8 * 8 + j, kb)] = col;
    }
    __syncthreads();   // bar2: P in SA, V in SB, psum visible

    f32x4 acc2[4][4];
    #pragma unroll
    for (int mi = 0; mi < 4; mi++)
        #pragma unroll
        for (int ni = 0; ni < 4; ni++) acc2[mi][ni] = (f32x4){0.f, 0.f, 0.f, 0.f};
    mfma64(SA, SB, acc2, lane, wr64, wc64);
    __syncthreads();   // bar3: SB free for output bounce

    #pragma unroll
    for (int mi = 0; mi < 4; mi++)
        #pragma unroll
        for (int r = 0; r < 4; r++) {
            int row = wr64 + mi * 16 + (lane >> 4) * 4 + r;
            float rinv = 1.f / (psum[0][row] + psum[1][row]);
            #pragma unroll
            for (int ni = 0; ni < 4; ni++) {
                int col = wc64 + ni * 16 + (lane & 15);
                short vv = f2b(acc2[mi][ni][r] * rinv);
                if (!TEPI) SB[swzb(row, col >> 3) + (col & 7)] = vv;
                else       SB[swzb(col, row >> 3) + (row & 7)] = vv;
            }
        }
    __syncthreads();
    #pragma unroll
    for (int i = 0; i < 8; i++) {
        int idx = t + i * 256;
        int row = idx >> 4, ch = idx & 15;
        *(bf16x8*)(Ob + (long long)row * 16384 + ch * 8) =
            *(const bf16x8*)&SB[swzb(row, ch)];
    }
}

extern "C" void kernel_launch(void* const* d_in, const int* in_sizes, int n_in,
                              void* d_out, int out_size, void* d_ws, size_t ws_size,
                              hipStream_t stream) {
    const float* x   = (const float*)d_in[0];
    const float* Wr  = (const float*)d_in[1];
    const float* br  = (const float*)d_in[2];
    const float* Wqw = (const float*)d_in[3];
    const float* bqw = (const float*)d_in[4];
    const float* Wkw = (const float*)d_in[5];
    const float* bkw = (const float*)d_in[6];
    const float* Wvw = (const float*)d_in[7];
    const float* bvw = (const float*)d_in[8];
    const float* Wqh = (const float*)d_in[9];
    const float* bqh = (const float*)d_in[10];
    const float* Wkh = (const float*)d_in[11];
    const float* bkh = (const float*)d_in[12];
    const float* Wvh = (const float*)d_in[13];
    const float* bvh = (const float*)d_in[14];
    const float* Wo  = (const float*)d_in[15];
    const float* bo  = (const float*)d_in[16];
    float* out = (float*)d_out;
    (void)in_sizes; (void)n_in; (void)out_size; (void)ws_size;

    // bf16 workspace, U = 8*128^3 elems (33.5MB). 4U tensors + weight images.
    // s0: rsz -> T1 -> T2 ; s1: q1 -> q2 ; s2: k1 -> k2 ; s3: v1 -> v2.
    const long long U = 16777216LL;
    short* wsp = (short*)d_ws;
    short* s0 = wsp;
    short* s1 = wsp + U;
    short* s2 = wsp + 2 * U;
    short* s3 = wsp + 3 * U;
    short* wb = wsp + 4 * U;
    short* wWr  = wb;
    short* wWqw = wb + 32768;
    short* wWkw = wb + 49152;
    short* wWvw = wb + 65536;
    short* wWqh = wb + 81920;
    short* wWkh = wb + 98304;
    short* wWvh = wb + 114688;
    short* wWo  = wb + 131072;

    dim3 blk(256);

    wprep<<<dim3(16, 8), blk, 0, stream>>>(Wr, Wqw, Wkw, Wvw, Wqh, Wkh, Wvh, Wo, wb);

    // P1: rsz[b][p][h][w] <- x, per (b,hw-tile); B fp32 n-fast, K=256
    gemmw<1, 2, 2, false><<<dim3(128, 1, 8), blk, 0, stream>>>(
        wWr, nullptr, nullptr, br, nullptr, nullptr,
        x, 4194304LL, 128LL, 16384LL,
        s0, nullptr, nullptr, nullptr, 2097152LL, 128LL, 16384LL);

    // P2: q1,k1,v1[b][o][.][w], per (b,p); B = rsz bf16 n-fast, NW=3
    gemmw<3, 1, 1, false><<<dim3(128, 1, 8), blk, 0, stream>>>(
        wWqw, wWkw, wWvw, bqw, bkw, bvw,
        s0, 2097152LL, 16384LL, 128LL,
        s1, s2, s3, nullptr, 2097152LL, 128LL, 16384LL);

    // P3: width attention -> T1[b][p][o][w] (into s0; rsz dead)
    attnk<false><<<dim3(128, 1, 8), blk, 0, stream>>>(s1, s2, s3, s0);

    // P4: q2,k2,v2, per (b,c); B = T1 k-fast, NW=3
    gemmw<3, 1, 0, false><<<dim3(128, 1, 8), blk, 0, stream>>>(
        wWqh, wWkh, wWvh, bqh, bkh, bvh,
        s0, 2097152LL, 16384LL, 128LL,
        s1, s2, s3, nullptr, 2097152LL, 128LL, 16384LL);

    // P5: height attention -> T2[b][h][o2][c] (into s0; T1 dead)
    attnk<true><<<dim3(128, 1, 8), blk, 0, stream>>>(s1, s2, s3, s0);

    // P6: out[b][co][h][o2] fp32, per (b,h), 2 m-tiles; B = T2 k-fast
    gemmw<1, 1, 0, true><<<dim3(128, 2, 8), blk, 0, stream>>>(
        wWo, nullptr, nullptr, bo, nullptr, nullptr,
        s0, 2097152LL, 16384LL, 128LL,
        nullptr, nullptr, nullptr, out, 4194304LL, 128LL, 16384LL);
}

// Round 7
// 235.284 us; speedup vs baseline: 4.2725x; 1.6686x over previous
//
#include <hip/hip_runtime.h>
#include <hip/hip_bf16.h>

// CSAA, round 7: round-4 structure (proven 279us) + occupancy-first GEMMs.
//  - gemmw64: M-tile 64 (As 16KB + Bs 32KB = 48KB -> 3 blocks/CU), NW up to 3
//    weights sharing one staged B panel, LDS-bounce coalesced epilogue
//    (round-4 style; fixes round-6's write amplification).
//  - gemm_p1: round-4 full-128 kernel (x must be read exactly once).
//  - attnk: round-4 verbatim.
// Pass graph (strides verbatim round 4):
//  P1 : rsz[b][p][h][w]    per (b,h)      B=x fp32 n-fast, K=256
//  P2 : q1,k1,v1[b][o][p][w] per (b,p,my) B=rsz bf16 n-fast (NW=3, MT64)
//  P3 : T1[b][p][o][w]     per (b,o)      flash attn
//  P4 : q2,k2,v2           per (b,c,my)   B=T1 k-fast gload16 (NW=3, MT64)
//  P5 : T2[b][h][o2][c]    per (b,o2)     flash attn, transposed epilogue
//  P6 : out[b][co][h][o2]  per (b,h,my4)  B=T2 k-fast, fp32 direct (MT64)

typedef __attribute__((ext_vector_type(8))) short bf16x8;
typedef __attribute__((ext_vector_type(4))) float f32x4;

__device__ __forceinline__ short f2b(float f) {
    __hip_bfloat16 h = __float2bfloat16(f);
    short s; __builtin_memcpy(&s, &h, 2);
    return s;
}

__device__ __forceinline__ int swx(int row) { return (row ^ (row >> 3)) & 7; }
__device__ __forceinline__ int swzb(int row, int blk) {
    return (row << 7) + ((blk ^ swx(row)) << 3);
}

__device__ __forceinline__ void gload16(const void* g, void* l) {
    __builtin_amdgcn_global_load_lds(
        (const __attribute__((address_space(1))) void*)g,
        (__attribute__((address_space(3))) void*)l, 16, 0, 0);
}

// 128x128 block, 4 waves of 64x64 (attn + P1).
__device__ __forceinline__ void mfma128(const short* __restrict__ SA,
                                        const short* __restrict__ SB,
                                        f32x4 (&acc)[4][4], int lane,
                                        int wr64, int wc64) {
    #pragma unroll
    for (int kk = 0; kk < 4; kk++) {
        const int kb = kk * 4 + (lane >> 4);
        bf16x8 a[4], b[4];
        #pragma unroll
        for (int mi = 0; mi < 4; mi++)
            a[mi] = *(const bf16x8*)&SA[swzb(wr64 + mi * 16 + (lane & 15), kb)];
        #pragma unroll
        for (int ni = 0; ni < 4; ni++)
            b[ni] = *(const bf16x8*)&SB[swzb(wc64 + ni * 16 + (lane & 15), kb)];
        #pragma unroll
        for (int mi = 0; mi < 4; mi++)
            #pragma unroll
            for (int ni = 0; ni < 4; ni++)
                acc[mi][ni] = __builtin_amdgcn_mfma_f32_16x16x32_bf16(
                    a[mi], b[ni], acc[mi][ni], 0, 0, 0);
    }
}

// 64x128 block, 4 waves of 32x64 (MT64 GEMMs).
__device__ __forceinline__ void mfma64x128(const short* __restrict__ SA,
                                           const short* __restrict__ SB,
                                           f32x4 (&acc)[2][4], int lane,
                                           int wr32, int wc64) {
    #pragma unroll
    for (int kk = 0; kk < 4; kk++) {
        const int kb = kk * 4 + (lane >> 4);
        bf16x8 a[2], b[4];
        #pragma unroll
        for (int mi = 0; mi < 2; mi++)
            a[mi] = *(const bf16x8*)&SA[swzb(wr32 + mi * 16 + (lane & 15), kb)];
        #pragma unroll
        for (int ni = 0; ni < 4; ni++)
            b[ni] = *(const bf16x8*)&SB[swzb(wc64 + ni * 16 + (lane & 15), kb)];
        #pragma unroll
        for (int mi = 0; mi < 2; mi++)
            #pragma unroll
            for (int ni = 0; ni < 4; ni++)
                acc[mi][ni] = __builtin_amdgcn_mfma_f32_16x16x32_bf16(
                    a[mi], b[ni], acc[mi][ni], 0, 0, 0);
    }
}

__device__ __forceinline__ void stage_nf_bf16(const short* __restrict__ Bb,
                                              long long b_r, int k0,
                                              short* __restrict__ Bs, int t) {
    const int n8 = t & 15, kb = t >> 4;
    bf16x8 rk[8];
    #pragma unroll
    for (int i = 0; i < 8; i++)
        rk[i] = *(const bf16x8*)(Bb + (long long)(k0 + kb * 8 + i) * b_r + n8 * 8);
    #pragma unroll
    for (int j = 0; j < 8; j++) {
        bf16x8 col;
        #pragma unroll
        for (int i = 0; i < 8; i++) col[i] = rk[i][j];
        *(bf16x8*)&Bs[swzb(n8 * 8 + j, kb)] = col;
    }
}

__device__ __forceinline__ void stage_nf_f32(const float* __restrict__ Bb,
                                             long long b_r, int k0,
                                             short* __restrict__ Bs, int t) {
    const int n8 = t & 15, kb = t >> 4;
    bf16x8 rk[8];
    #pragma unroll
    for (int i = 0; i < 8; i++) {
        const float* s = Bb + (long long)(k0 + kb * 8 + i) * b_r + n8 * 8;
        float4 v0 = *(const float4*)s, v1 = *(const float4*)(s + 4);
        rk[i][0] = f2b(v0.x); rk[i][1] = f2b(v0.y);
        rk[i][2] = f2b(v0.z); rk[i][3] = f2b(v0.w);
        rk[i][4] = f2b(v1.x); rk[i][5] = f2b(v1.y);
        rk[i][6] = f2b(v1.z); rk[i][7] = f2b(v1.w);
    }
    #pragma unroll
    for (int j = 0; j < 8; j++) {
        bf16x8 col;
        #pragma unroll
        for (int i = 0; i < 8; i++) col[i] = rk[i][j];
        *(bf16x8*)&Bs[swzb(n8 * 8 + j, kb)] = col;
    }
}

// ---------------- wprep: fp32 weights -> bf16 page-swizzled images ---------
// Page (my,ks): 16384 elems; element swzb(r,bi) = W[my*128+r][ks*128+bi*8..].
// Loaded LINEARLY into LDS and read with swzb(). Half-pages (64 rows) are
// self-consistent: swx(64+r') == swx(r').
__global__ __launch_bounds__(256)
void wprep(const float* __restrict__ Wr, const float* __restrict__ Wqw,
           const float* __restrict__ Wkw, const float* __restrict__ Wvw,
           const float* __restrict__ Wqh, const float* __restrict__ Wkh,
           const float* __restrict__ Wvh, const float* __restrict__ Wo,
           short* __restrict__ dst) {
    const int id = blockIdx.y;
    const float* W; int M, K, off;
    switch (id) {
        case 0: W = Wr;  M = 128; K = 256; off = 0;      break;
        case 1: W = Wqw; M = 128; K = 128; off = 32768;  break;
        case 2: W = Wkw; M = 128; K = 128; off = 49152;  break;
        case 3: W = Wvw; M = 128; K = 128; off = 65536;  break;
        case 4: W = Wqh; M = 128; K = 128; off = 81920;  break;
        case 5: W = Wkh; M = 128; K = 128; off = 98304;  break;
        case 6: W = Wvh; M = 128; K = 128; off = 114688; break;
        default: W = Wo; M = 256; K = 128; off = 131072; break;
    }
    int g = blockIdx.x * 256 + threadIdx.x;
    if (g >= (M * K) >> 3) return;
    int gpr = K >> 3;
    int row = g / gpr;
    int blk = g - row * gpr;
    int ks = blk >> 4, bi = blk & 15;
    int my = row >> 7, r = row & 127;
    int nks = K >> 7;
    const float* s = W + (long long)row * K + blk * 8;
    float4 v0 = *(const float4*)s, v1 = *(const float4*)(s + 4);
    bf16x8 ov;
    ov[0] = f2b(v0.x); ov[1] = f2b(v0.y); ov[2] = f2b(v0.z); ov[3] = f2b(v0.w);
    ov[4] = f2b(v1.x); ov[5] = f2b(v1.y); ov[6] = f2b(v1.z); ov[7] = f2b(v1.w);
    *(bf16x8*)(dst + off + (my * nks + ks) * 16384 + swzb(r, bi)) = ov;
}

// ---------------- P1: full 128-tile, K=256, B = x fp32 n-fast --------------
__global__ __launch_bounds__(256)
void gemm_p1(const short* __restrict__ A0, const float* __restrict__ bias0,
             const float* __restrict__ Bsrc,
             long long b_z, long long b_x, long long b_r,
             short* __restrict__ C0,
             long long c_z, long long c_x, long long c_m) {
    __shared__ short As[16384];
    __shared__ short Bs[16384];
    const int t = threadIdx.x;
    const int lane = t & 63;
    const int wid = t >> 6;
    const int wr64 = (wid >> 1) * 64, wc64 = (wid & 1) * 64;
    const int bx = blockIdx.x, bz = blockIdx.z;

    f32x4 acc[4][4];
    #pragma unroll
    for (int mi = 0; mi < 4; mi++)
        #pragma unroll
        for (int ni = 0; ni < 4; ni++) acc[mi][ni] = (f32x4){0.f, 0.f, 0.f, 0.f};

    for (int ks = 0; ks < 2; ks++) {
        if (ks) __syncthreads();
        stage_nf_f32(Bsrc + bz * b_z + bx * b_x, b_r, ks * 128, Bs, t);
        const short* Ai = A0 + ks * 16384;
        #pragma unroll
        for (int i = 0; i < 8; i++) {
            int q = wid * 8 + i;
            gload16(Ai + q * 512 + lane * 8, &As[q * 512]);
        }
        __syncthreads();
        mfma128(As, Bs, acc, lane, wr64, wc64);
    }
    __syncthreads();

    // bounce -> coalesced bf16x8 stores
    #pragma unroll
    for (int mi = 0; mi < 4; mi++)
        #pragma unroll
        for (int r = 0; r < 4; r++) {
            int row = wr64 + mi * 16 + (lane >> 4) * 4 + r;
            float bb = bias0[row];
            #pragma unroll
            for (int ni = 0; ni < 4; ni++) {
                int col = wc64 + ni * 16 + (lane & 15);
                As[swzb(row, col >> 3) + (col & 7)] = f2b(acc[mi][ni][r] + bb);
            }
        }
    __syncthreads();
    short* Cg = C0 + bz * c_z + bx * c_x;
    #pragma unroll
    for (int i = 0; i < 8; i++) {
        int idx = t + i * 256;
        int row = idx >> 4, ch = idx & 15;
        *(bf16x8*)(Cg + (long long)row * c_m + ch * 8) =
            *(const bf16x8*)&As[swzb(row, ch)];
    }
}

// ---------------- MT64 weight-GEMM: 64x128 tile, 3 blocks/CU ---------------
// BMODE: 0 = B k-fast (gload16), 1 = B n-fast bf16. K=128 (one step).
template<int NW, int BMODE, bool F32OUT>
__global__ __launch_bounds__(256, 3)
void gemmw64(const short* __restrict__ A0, const short* __restrict__ A1,
             const short* __restrict__ A2,
             const float* __restrict__ bias0, const float* __restrict__ bias1,
             const float* __restrict__ bias2,
             const void* __restrict__ Bsrc, long long b_z, long long b_x,
             long long b_r,
             short* __restrict__ C0, short* __restrict__ C1,
             short* __restrict__ C2, float* __restrict__ Cf,
             long long c_z, long long c_x, long long c_m) {
    __shared__ short As[8192];     // 64 rows x 128 k
    __shared__ short Bs[16384];    // 128 n x 128 k
    const int t = threadIdx.x;
    const int lane = t & 63;
    const int wid = t >> 6;
    const int wr32 = (wid >> 1) * 32, wc64 = (wid & 1) * 64;
    const int bx = blockIdx.x, my = blockIdx.y, bz = blockIdx.z;
    const int mbase = my * 64;

    // stage B once
    if (BMODE == 0) {
        const short* Bb = (const short*)Bsrc + bz * b_z + bx * b_x;
        #pragma unroll
        for (int i = 0; i < 8; i++) {
            int q = wid * 8 + i;
            int row = q * 4 + (lane >> 4);
            gload16(Bb + (long long)row * b_r + (((lane & 15) ^ swx(row)) << 3),
                    &Bs[q * 512]);
        }
    } else {
        stage_nf_bf16((const short*)Bsrc + bz * b_z + bx * b_x, b_r, 0, Bs, t);
    }

    #pragma unroll
    for (int g = 0; g < NW; g++) {
        if (g) __syncthreads();   // protect As from prior store reads
        // stage A half-page (16KB): image page + my*8192, linear
        const short* Ai = ((g == 0) ? A0 : (g == 1) ? A1 : A2) + my * 8192;
        #pragma unroll
        for (int i = 0; i < 4; i++) {
            int q = wid * 4 + i;
            gload16(Ai + q * 512 + lane * 8, &As[q * 512]);
        }
        __syncthreads();

        f32x4 acc[2][4];
        #pragma unroll
        for (int mi = 0; mi < 2; mi++)
            #pragma unroll
            for (int ni = 0; ni < 4; ni++)
                acc[mi][ni] = (f32x4){0.f, 0.f, 0.f, 0.f};
        mfma64x128(As, Bs, acc, lane, wr32, wc64);

        const float* bias = (g == 0) ? bias0 : (g == 1) ? bias1 : bias2;
        if (F32OUT) {
            float* Cb = Cf + bz * c_z + bx * c_x;
            #pragma unroll
            for (int mi = 0; mi < 2; mi++)
                #pragma unroll
                for (int r = 0; r < 4; r++) {
                    int row = mbase + wr32 + mi * 16 + (lane >> 4) * 4 + r;
                    float bb = bias[row];
                    float* cp = Cb + (long long)row * c_m + wc64 + (lane & 15);
                    #pragma unroll
                    for (int ni = 0; ni < 4; ni++)
                        cp[ni * 16] = acc[mi][ni][r] + bb;
                }
        } else {
            __syncthreads();   // all waves done reading As
            #pragma unroll
            for (int mi = 0; mi < 2; mi++)
                #pragma unroll
                for (int r = 0; r < 4; r++) {
                    int row = wr32 + mi * 16 + (lane >> 4) * 4 + r;  // < 64
                    float bb = bias[mbase + row];
                    #pragma unroll
                    for (int ni = 0; ni < 4; ni++) {
                        int col = wc64 + ni * 16 + (lane & 15);
                        As[swzb(row, col >> 3) + (col & 7)] =
                            f2b(acc[mi][ni][r] + bb);
                    }
                }
            __syncthreads();
            short* Cg = ((g == 0) ? C0 : (g == 1) ? C1 : C2)
                      + bz * c_z + bx * c_x;
            #pragma unroll
            for (int i = 0; i < 4; i++) {
                int idx = t + i * 256;          // 0..1023 = 64 rows x 16 chunks
                int row = idx >> 4, ch = idx & 15;
                *(bf16x8*)(Cg + (long long)(mbase + row) * c_m + ch * 8) =
                    *(const bf16x8*)&As[swzb(row, ch)];
            }
        }
    }
}

// ---------------- fused attention per (b,o) (round-4 verbatim) -------------
template<bool TEPI>
__global__ __launch_bounds__(256)
void attnk(const short* __restrict__ Q, const short* __restrict__ Kp,
           const short* __restrict__ V, short* __restrict__ O) {
    __shared__ short SA[16384];
    __shared__ short SB[16384];
    __shared__ float pmax[2][128];
    __shared__ float psum[2][128];
    const int t = threadIdx.x;
    const int lane = t & 63;
    const int wid = t >> 6;
    const int wr64 = (wid >> 1) * 64, wc64 = (wid & 1) * 64, wch = wid & 1;
    const long long poff = (long long)blockIdx.z * 2097152LL
                         + (long long)blockIdx.x * 16384LL;
    const short* Qb = Q + poff;
    const short* Kb = Kp + poff;
    const short* Vb = V + poff;
    short* Ob = O + (long long)blockIdx.z * 2097152LL + (long long)blockIdx.x * 128LL;

    #pragma unroll
    for (int i = 0; i < 8; i++) {
        int q = wid * 8 + i;
        int row = q * 4 + (lane >> 4);
        int sw = (((lane & 15) ^ swx(row)) << 3);
        gload16(Qb + row * 128 + sw, &SA[q * 512]);
        gload16(Kb + row * 128 + sw, &SB[q * 512]);
    }
    __syncthreads();

    f32x4 acc[4][4];
    #pragma unroll
    for (int mi = 0; mi < 4; mi++)
        #pragma unroll
        for (int ni = 0; ni < 4; ni++) acc[mi][ni] = (f32x4){0.f, 0.f, 0.f, 0.f};
    mfma128(SA, SB, acc, lane, wr64, wc64);

    #pragma unroll
    for (int mi = 0; mi < 4; mi++)
        #pragma unroll
        for (int r = 0; r < 4; r++) {
            float mx = fmaxf(fmaxf(acc[mi][0][r], acc[mi][1][r]),
                             fmaxf(acc[mi][2][r], acc[mi][3][r]));
            #pragma unroll
            for (int d = 1; d < 16; d <<= 1) mx = fmaxf(mx, __shfl_xor(mx, d, 64));
            if ((lane & 15) == 0)
                pmax[wch][wr64 + mi * 16 + (lane >> 4) * 4 + r] = mx;
        }
    __syncthreads();   // bar1

    const int n8 = t & 15, kb = t >> 4;
    bf16x8 vk[8];
    #pragma unroll
    for (int i = 0; i < 8; i++)
        vk[i] = *(const bf16x8*)(Vb + (kb * 8 + i) * 128 + n8 * 8);

    #pragma unroll
    for (int mi = 0; mi < 4; mi++)
        #pragma unroll
        for (int r = 0; r < 4; r++) {
            int row = wr64 + mi * 16 + (lane >> 4) * 4 + r;
            float M = fmaxf(pmax[0][row], pmax[1][row]);
            float p[4], s = 0.f;
            #pragma unroll
            for (int ni = 0; ni < 4; ni++) {
                p[ni] = __expf(acc[mi][ni][r] - M);
                s += p[ni];
            }
            #pragma unroll
            for (int d = 1; d < 16; d <<= 1) s += __shfl_xor(s, d, 64);
            if ((lane & 15) == 0) psum[wch][row] = s;
            #pragma unroll
            for (int ni = 0; ni < 4; ni++) {
                int col = wc64 + ni * 16 + (lane & 15);
                SA[swzb(row, col >> 3) + (col & 7)] = f2b(p[ni]);
            }
        }
    #pragma unroll
    for (int j = 0; j < 8; j++) {
        bf16x8 col;
        #pragma unroll
        for (int i = 0; i < 8; i++) col[i] = vk[i][j];
        *(bf16x8*)&SB[swzb(n8 * 8 + j, kb)] = col;
    }
    __syncthreads();   // bar2

    f32x4 acc2[4][4];
    #pragma unroll
    for (int mi = 0; mi < 4; mi++)
        #pragma unroll
        for (int ni = 0; ni < 4; ni++) acc2[mi][ni] = (f32x4){0.f, 0.f, 0.f, 0.f};
    mfma128(SA, SB, acc2, lane, wr64, wc64);
    __syncthreads();   // bar3

    #pragma unroll
    for (int mi = 0; mi < 4; mi++)
        #pragma unroll
        for (int r = 0; r < 4; r++) {
            int row = wr64 + mi * 16 + (lane >> 4) * 4 + r;
            float rinv = 1.f / (psum[0][row] + psum[1][row]);
            #pragma unroll
            for (int ni = 0; ni < 4; ni++) {
                int col = wc64 + ni * 16 + (lane & 15);
                short vv = f2b(acc2[mi][ni][r] * rinv);
                if (!TEPI) SB[swzb(row, col >> 3) + (col & 7)] = vv;
                else       SB[swzb(col, row >> 3) + (row & 7)] = vv;
            }
        }
    __syncthreads();
    #pragma unroll
    for (int i = 0; i < 8; i++) {
        int idx = t + i * 256;
        int row = idx >> 4, ch = idx & 15;
        *(bf16x8*)(Ob + (long long)row * 16384 + ch * 8) =
            *(const bf16x8*)&SB[swzb(row, ch)];
    }
}

extern "C" void kernel_launch(void* const* d_in, const int* in_sizes, int n_in,
                              void* d_out, int out_size, void* d_ws, size_t ws_size,
                              hipStream_t stream) {
    const float* x   = (const float*)d_in[0];
    const float* Wr  = (const float*)d_in[1];
    const float* br  = (const float*)d_in[2];
    const float* Wqw = (const float*)d_in[3];
    const float* bqw = (const float*)d_in[4];
    const float* Wkw = (const float*)d_in[5];
    const float* bkw = (const float*)d_in[6];
    const float* Wvw = (const float*)d_in[7];
    const float* bvw = (const float*)d_in[8];
    const float* Wqh = (const float*)d_in[9];
    const float* bqh = (const float*)d_in[10];
    const float* Wkh = (const float*)d_in[11];
    const float* bkh = (const float*)d_in[12];
    const float* Wvh = (const float*)d_in[13];
    const float* bvh = (const float*)d_in[14];
    const float* Wo  = (const float*)d_in[15];
    const float* bo  = (const float*)d_in[16];
    float* out = (float*)d_out;
    (void)in_sizes; (void)n_in; (void)out_size; (void)ws_size;

    // bf16 workspace, U = 8*128^3 elems (33.5MB). 4U tensors + weight images.
    // s0: rsz -> T1 -> T2 ; s1: q1 -> q2 ; s2: k1 -> k2 ; s3: v1 -> v2.
    const long long U = 16777216LL;
    short* wsp = (short*)d_ws;
    short* s0 = wsp;
    short* s1 = wsp + U;
    short* s2 = wsp + 2 * U;
    short* s3 = wsp + 3 * U;
    short* wb = wsp + 4 * U;
    short* wWr  = wb;
    short* wWqw = wb + 32768;
    short* wWkw = wb + 49152;
    short* wWvw = wb + 65536;
    short* wWqh = wb + 81920;
    short* wWkh = wb + 98304;
    short* wWvh = wb + 114688;
    short* wWo  = wb + 131072;

    dim3 blk(256);

    wprep<<<dim3(16, 8), blk, 0, stream>>>(Wr, Wqw, Wkw, Wvw, Wqh, Wkh, Wvh, Wo, wb);

    // P1: rsz[b][p][h][w] <- x, per (b,h-chunk); B fp32 n-fast, K=256
    gemm_p1<<<dim3(128, 1, 8), blk, 0, stream>>>(
        wWr, br, x, 4194304LL, 128LL, 16384LL,
        s0, 2097152LL, 128LL, 16384LL);

    // P2: q1,k1,v1[b][o][p][w], per (b,p,my); B = rsz bf16 n-fast, NW=3
    gemmw64<3, 1, false><<<dim3(128, 2, 8), blk, 0, stream>>>(
        wWqw, wWkw, wWvw, bqw, bkw, bvw,
        s0, 2097152LL, 16384LL, 128LL,
        s1, s2, s3, nullptr, 2097152LL, 128LL, 16384LL);

    // P3: width attention -> T1[b][p][o][w] (into s0; rsz dead)
    attnk<false><<<dim3(128, 1, 8), blk, 0, stream>>>(s1, s2, s3, s0);

    // P4: q2,k2,v2, per (b,c,my); B = T1 k-fast, NW=3
    gemmw64<3, 0, false><<<dim3(128, 2, 8), blk, 0, stream>>>(
        wWqh, wWkh, wWvh, bqh, bkh, bvh,
        s0, 2097152LL, 16384LL, 128LL,
        s1, s2, s3, nullptr, 2097152LL, 128LL, 16384LL);

    // P5: height attention -> T2[b][h][o2][c] (into s0; T1 dead)
    attnk<true><<<dim3(128, 1, 8), blk, 0, stream>>>(s1, s2, s3, s0);

    // P6: out[b][co][h][o2] fp32, per (b,h,my4); B = T2 k-fast
    gemmw64<1, 0, true><<<dim3(128, 4, 8), blk, 0, stream>>>(
        wWo, nullptr, nullptr, bo, nullptr, nullptr,
        s0, 2097152LL, 16384LL, 128LL,
        nullptr, nullptr, nullptr, out, 4194304LL, 128LL, 16384LL);
}

// Round 8
// 216.704 us; speedup vs baseline: 4.6389x; 1.0857x over previous
//
#include <hip/hip_runtime.h>
#include <hip/hip_bf16.h>

// CSAA, round 8: round-7 graph (proven 235us) with wave-owns-rows tiling.
// Each wave computes M-rows x full N=128 (acc[.][8]); A-staging, epilogue
// bounce and C-store are wave-local -> barriers collapse:
//   gemmw64: ~10 -> 3 barriers ; gemm_p1: 6 -> 3 ; attnk: 5 -> 3 (non-TEPI,
//   plus register-only softmax, pmax/psum LDS removed).
// All global layouts / strides verbatim round 7.
//  P1 : rsz[b][p][h][w]    per (b,h)      B=x fp32 n-fast, K=256
//  P2 : q1,k1,v1[b][o][p][w] per (b,p,my) B=rsz bf16 n-fast (NW=3, MT64)
//  P3 : T1[b][p][o][w]     per (b,o)      flash attn
//  P4 : q2,k2,v2           per (b,c,my)   B=T1 k-fast gload16 (NW=3, MT64)
//  P5 : T2[b][h][o2][c]    per (b,o2)     flash attn, transposed epilogue
//  P6 : out[b][co][h][o2]  per (b,h,my4)  B=T2 k-fast, fp32 direct (MT64)

typedef __attribute__((ext_vector_type(8))) short bf16x8;
typedef __attribute__((ext_vector_type(4))) float f32x4;

__device__ __forceinline__ short f2b(float f) {
    __hip_bfloat16 h = __float2bfloat16(f);
    short s; __builtin_memcpy(&s, &h, 2);
    return s;
}

__device__ __forceinline__ int swx(int row) { return (row ^ (row >> 3)) & 7; }
__device__ __forceinline__ int swzb(int row, int blk) {
    return (row << 7) + ((blk ^ swx(row)) << 3);
}

__device__ __forceinline__ void gload16(const void* g, void* l) {
    __builtin_amdgcn_global_load_lds(
        (const __attribute__((address_space(1))) void*)g,
        (__attribute__((address_space(3))) void*)l, 16, 0, 0);
}

// wave computes 32 rows x 128 cols: acc[2][8]; A rows are wave-local [wr,wr+32).
__device__ __forceinline__ void mfma32x128(const short* __restrict__ SA,
                                           const short* __restrict__ SB,
                                           f32x4 (&acc)[2][8], int lane, int wr) {
    #pragma unroll
    for (int kk = 0; kk < 4; kk++) {
        const int kb = kk * 4 + (lane >> 4);
        bf16x8 a[2], b[8];
        #pragma unroll
        for (int mi = 0; mi < 2; mi++)
            a[mi] = *(const bf16x8*)&SA[swzb(wr + mi * 16 + (lane & 15), kb)];
        #pragma unroll
        for (int ni = 0; ni < 8; ni++)
            b[ni] = *(const bf16x8*)&SB[swzb(ni * 16 + (lane & 15), kb)];
        #pragma unroll
        for (int mi = 0; mi < 2; mi++)
            #pragma unroll
            for (int ni = 0; ni < 8; ni++)
                acc[mi][ni] = __builtin_amdgcn_mfma_f32_16x16x32_bf16(
                    a[mi], b[ni], acc[mi][ni], 0, 0, 0);
    }
}

// wave computes 16 rows x 128 cols: acc[8]; A rows wave-local [wr16, wr16+16).
__device__ __forceinline__ void mfma16x128(const short* __restrict__ SA,
                                           const short* __restrict__ SB,
                                           f32x4 (&acc)[8], int lane, int wr16) {
    #pragma unroll
    for (int kk = 0; kk < 4; kk++) {
        const int kb = kk * 4 + (lane >> 4);
        bf16x8 a = *(const bf16x8*)&SA[swzb(wr16 + (lane & 15), kb)];
        bf16x8 b[8];
        #pragma unroll
        for (int ni = 0; ni < 8; ni++)
            b[ni] = *(const bf16x8*)&SB[swzb(ni * 16 + (lane & 15), kb)];
        #pragma unroll
        for (int ni = 0; ni < 8; ni++)
            acc[ni] = __builtin_amdgcn_mfma_f32_16x16x32_bf16(
                a, b[ni], acc[ni], 0, 0, 0);
    }
}

__device__ __forceinline__ void stage_nf_bf16(const short* __restrict__ Bb,
                                              long long b_r, int k0,
                                              short* __restrict__ Bs, int t) {
    const int n8 = t & 15, kb = t >> 4;
    bf16x8 rk[8];
    #pragma unroll
    for (int i = 0; i < 8; i++)
        rk[i] = *(const bf16x8*)(Bb + (long long)(k0 + kb * 8 + i) * b_r + n8 * 8);
    #pragma unroll
    for (int j = 0; j < 8; j++) {
        bf16x8 col;
        #pragma unroll
        for (int i = 0; i < 8; i++) col[i] = rk[i][j];
        *(bf16x8*)&Bs[swzb(n8 * 8 + j, kb)] = col;
    }
}

__device__ __forceinline__ void stage_nf_f32(const float* __restrict__ Bb,
                                             long long b_r, int k0,
                                             short* __restrict__ Bs, int t) {
    const int n8 = t & 15, kb = t >> 4;
    bf16x8 rk[8];
    #pragma unroll
    for (int i = 0; i < 8; i++) {
        const float* s = Bb + (long long)(k0 + kb * 8 + i) * b_r + n8 * 8;
        float4 v0 = *(const float4*)s, v1 = *(const float4*)(s + 4);
        rk[i][0] = f2b(v0.x); rk[i][1] = f2b(v0.y);
        rk[i][2] = f2b(v0.z); rk[i][3] = f2b(v0.w);
        rk[i][4] = f2b(v1.x); rk[i][5] = f2b(v1.y);
        rk[i][6] = f2b(v1.z); rk[i][7] = f2b(v1.w);
    }
    #pragma unroll
    for (int j = 0; j < 8; j++) {
        bf16x8 col;
        #pragma unroll
        for (int i = 0; i < 8; i++) col[i] = rk[i][j];
        *(bf16x8*)&Bs[swzb(n8 * 8 + j, kb)] = col;
    }
}

// ---------------- wprep: fp32 weights -> bf16 page-swizzled images ---------
__global__ __launch_bounds__(256)
void wprep(const float* __restrict__ Wr, const float* __restrict__ Wqw,
           const float* __restrict__ Wkw, const float* __restrict__ Wvw,
           const float* __restrict__ Wqh, const float* __restrict__ Wkh,
           const float* __restrict__ Wvh, const float* __restrict__ Wo,
           short* __restrict__ dst) {
    const int id = blockIdx.y;
    const float* W; int M, K, off;
    switch (id) {
        case 0: W = Wr;  M = 128; K = 256; off = 0;      break;
        case 1: W = Wqw; M = 128; K = 128; off = 32768;  break;
        case 2: W = Wkw; M = 128; K = 128; off = 49152;  break;
        case 3: W = Wvw; M = 128; K = 128; off = 65536;  break;
        case 4: W = Wqh; M = 128; K = 128; off = 81920;  break;
        case 5: W = Wkh; M = 128; K = 128; off = 98304;  break;
        case 6: W = Wvh; M = 128; K = 128; off = 114688; break;
        default: W = Wo; M = 256; K = 128; off = 131072; break;
    }
    int g = blockIdx.x * 256 + threadIdx.x;
    if (g >= (M * K) >> 3) return;
    int gpr = K >> 3;
    int row = g / gpr;
    int blk = g - row * gpr;
    int ks = blk >> 4, bi = blk & 15;
    int my = row >> 7, r = row & 127;
    int nks = K >> 7;
    const float* s = W + (long long)row * K + blk * 8;
    float4 v0 = *(const float4*)s, v1 = *(const float4*)(s + 4);
    bf16x8 ov;
    ov[0] = f2b(v0.x); ov[1] = f2b(v0.y); ov[2] = f2b(v0.z); ov[3] = f2b(v0.w);
    ov[4] = f2b(v1.x); ov[5] = f2b(v1.y); ov[6] = f2b(v1.z); ov[7] = f2b(v1.w);
    *(bf16x8*)(dst + off + (my * nks + ks) * 16384 + swzb(r, bi)) = ov;
}

// ---------------- P1: 128-tile, K=256, wave-owns-32-rows, 3 barriers -------
__global__ __launch_bounds__(256)
void gemm_p1(const short* __restrict__ A0, const float* __restrict__ bias0,
             const float* __restrict__ Bsrc,
             long long b_z, long long b_x, long long b_r,
             short* __restrict__ C0,
             long long c_z, long long c_x, long long c_m) {
    __shared__ short As[16384];
    __shared__ short Bs[16384];
    const int t = threadIdx.x;
    const int lane = t & 63;
    const int wid = t >> 6;
    const int wr = wid * 32;
    const int bx = blockIdx.x, bz = blockIdx.z;

    f32x4 acc[2][8];
    #pragma unroll
    for (int mi = 0; mi < 2; mi++)
        #pragma unroll
        for (int ni = 0; ni < 8; ni++) acc[mi][ni] = (f32x4){0.f, 0.f, 0.f, 0.f};

    #pragma unroll
    for (int ks = 0; ks < 2; ks++) {
        if (ks) __syncthreads();                       // all done reading Bs
        stage_nf_f32(Bsrc + bz * b_z + bx * b_x, b_r, ks * 128, Bs, t);
        const short* Ai = A0 + ks * 16384;
        #pragma unroll
        for (int i = 0; i < 8; i++) {
            int q = wid * 8 + i;                       // wave-local rows
            gload16(Ai + q * 512 + lane * 8, &As[q * 512]);
        }
        __syncthreads();
        mfma32x128(As, Bs, acc, lane, wr);
    }

    // wave-local epilogue: bounce into own As rows, store own rows
    #pragma unroll
    for (int mi = 0; mi < 2; mi++)
        #pragma unroll
        for (int r = 0; r < 4; r++) {
            int row = wr + mi * 16 + (lane >> 4) * 4 + r;
            float bb = bias0[row];
            #pragma unroll
            for (int ni = 0; ni < 8; ni++) {
                int col = ni * 16 + (lane & 15);
                As[swzb(row, col >> 3) + (col & 7)] = f2b(acc[mi][ni][r] + bb);
            }
        }
    short* Cg = C0 + bz * c_z + bx * c_x;
    #pragma unroll
    for (int i = 0; i < 8; i++) {
        int idx = lane + i * 64;
        int row = wr + (idx >> 4), ch = idx & 15;
        *(bf16x8*)(Cg + (long long)row * c_m + ch * 8) =
            *(const bf16x8*)&As[swzb(row, ch)];
    }
}

// ---------------- MT64 weight-GEMM: wave-owns-16-rows, NW barriers ---------
template<int NW, int BMODE, bool F32OUT>
__global__ __launch_bounds__(256, 3)
void gemmw64(const short* __restrict__ A0, const short* __restrict__ A1,
             const short* __restrict__ A2,
             const float* __restrict__ bias0, const float* __restrict__ bias1,
             const float* __restrict__ bias2,
             const void* __restrict__ Bsrc, long long b_z, long long b_x,
             long long b_r,
             short* __restrict__ C0, short* __restrict__ C1,
             short* __restrict__ C2, float* __restrict__ Cf,
             long long c_z, long long c_x, long long c_m) {
    __shared__ short As[8192];     // 64 rows x 128 k
    __shared__ short Bs[16384];    // 128 n x 128 k
    const int t = threadIdx.x;
    const int lane = t & 63;
    const int wid = t >> 6;
    const int wr16 = wid * 16;
    const int bx = blockIdx.x, my = blockIdx.y, bz = blockIdx.z;
    const int mbase = my * 64;

    // stage B (cooperative)
    if (BMODE == 0) {
        const short* Bb = (const short*)Bsrc + bz * b_z + bx * b_x;
        #pragma unroll
        for (int i = 0; i < 8; i++) {
            int q = wid * 8 + i;
            int row = q * 4 + (lane >> 4);
            gload16(Bb + (long long)row * b_r + (((lane & 15) ^ swx(row)) << 3),
                    &Bs[q * 512]);
        }
    } else {
        stage_nf_bf16((const short*)Bsrc + bz * b_z + bx * b_x, b_r, 0, Bs, t);
    }
    // stage A g=0 (wave-local rows [wr16, wr16+16))
    {
        const short* Ai = A0 + my * 8192;
        #pragma unroll
        for (int i = 0; i < 4; i++) {
            int q = wid * 4 + i;
            gload16(Ai + q * 512 + lane * 8, &As[q * 512]);
        }
    }
    __syncthreads();

    #pragma unroll
    for (int g = 0; g < NW; g++) {
        const float* bias = (g == 0) ? bias0 : (g == 1) ? bias1 : bias2;
        f32x4 acc[8];
        #pragma unroll
        for (int ni = 0; ni < 8; ni++) acc[ni] = (f32x4){0.f, 0.f, 0.f, 0.f};
        mfma16x128(As, Bs, acc, lane, wr16);

        if (F32OUT) {
            float* Cb = Cf + bz * c_z + bx * c_x;
            #pragma unroll
            for (int r = 0; r < 4; r++) {
                int row = mbase + wr16 + (lane >> 4) * 4 + r;
                float bb = bias[row];
                float* cp = Cb + (long long)row * c_m + (lane & 15);
                #pragma unroll
                for (int ni = 0; ni < 8; ni++)
                    cp[ni * 16] = acc[ni][r] + bb;
            }
        } else {
            // wave-local bounce into own As rows + store own rows
            #pragma unroll
            for (int r = 0; r < 4; r++) {
                int row = wr16 + (lane >> 4) * 4 + r;
                float bb = bias[mbase + row];
                #pragma unroll
                for (int ni = 0; ni < 8; ni++) {
                    int col = ni * 16 + (lane & 15);
                    As[swzb(row, col >> 3) + (col & 7)] = f2b(acc[ni][r] + bb);
                }
            }
            short* Cg = ((g == 0) ? C0 : (g == 1) ? C1 : C2)
                      + bz * c_z + bx * c_x;
            #pragma unroll
            for (int i = 0; i < 4; i++) {
                int idx = lane + i * 64;
                int row = wr16 + (idx >> 4), ch = idx & 15;
                *(bf16x8*)(Cg + (long long)(mbase + row) * c_m + ch * 8) =
                    *(const bf16x8*)&As[swzb(row, ch)];
            }
        }
        if (g + 1 < NW) {
            // restage A for g+1 (wave-local; prior ds_reads drained by data dep)
            const short* Ai = ((g == 0) ? A1 : A2) + my * 8192;
            #pragma unroll
            for (int i = 0; i < 4; i++) {
                int q = wid * 4 + i;
                gload16(Ai + q * 512 + lane * 8, &As[q * 512]);
            }
            __syncthreads();   // drains vmcnt before next mfma
        }
    }
}

// ---------------- fused attention per (b,o): wave-owns-32-rows -------------
// Register softmax (full S-row in wave: 8 regs x 16 lanes). Unscaled P;
// 1/rowsum folded into PV epilogue. 3 barriers (non-TEPI) / 5 (TEPI).
template<bool TEPI>
__global__ __launch_bounds__(256)
void attnk(const short* __restrict__ Q, const short* __restrict__ Kp,
           const short* __restrict__ V, short* __restrict__ O) {
    __shared__ short SA[16384];
    __shared__ short SB[16384];
    const int t = threadIdx.x;
    const int lane = t & 63;
    const int wid = t >> 6;
    const int wr = wid * 32;
    const long long poff = (long long)blockIdx.z * 2097152LL
                         + (long long)blockIdx.x * 16384LL;
    const short* Qb = Q + poff;
    const short* Kb = Kp + poff;
    const short* Vb = V + poff;
    short* Ob = O + (long long)blockIdx.z * 2097152LL + (long long)blockIdx.x * 128LL;

    // stage Q (wave-local rows) + K (cooperative)
    #pragma unroll
    for (int i = 0; i < 8; i++) {
        int q = wid * 8 + i;
        int row = q * 4 + (lane >> 4);
        int sw = (((lane & 15) ^ swx(row)) << 3);
        gload16(Qb + row * 128 + sw, &SA[q * 512]);
        gload16(Kb + row * 128 + sw, &SB[q * 512]);
    }
    // V register loads (cooperative; consumed after bar2)
    const int n8 = t & 15, kb = t >> 4;
    bf16x8 vk[8];
    #pragma unroll
    for (int i = 0; i < 8; i++)
        vk[i] = *(const bf16x8*)(Vb + (kb * 8 + i) * 128 + n8 * 8);
    __syncthreads();   // bar1: Q,K staged

    f32x4 acc[2][8];
    #pragma unroll
    for (int mi = 0; mi < 2; mi++)
        #pragma unroll
        for (int ni = 0; ni < 8; ni++) acc[mi][ni] = (f32x4){0.f, 0.f, 0.f, 0.f};
    mfma32x128(SA, SB, acc, lane, wr);

    // register softmax per row; write unscaled P into own SA rows
    float rs[2][4];
    #pragma unroll
    for (int mi = 0; mi < 2; mi++)
        #pragma unroll
        for (int r = 0; r < 4; r++) {
            float mx = acc[mi][0][r];
            #pragma unroll
            for (int ni = 1; ni < 8; ni++) mx = fmaxf(mx, acc[mi][ni][r]);
            #pragma unroll
            for (int d = 1; d < 16; d <<= 1) mx = fmaxf(mx, __shfl_xor(mx, d, 64));
            float s = 0.f;
            float p[8];
            #pragma unroll
            for (int ni = 0; ni < 8; ni++) {
                p[ni] = __expf(acc[mi][ni][r] - mx);
                s += p[ni];
            }
            #pragma unroll
            for (int d = 1; d < 16; d <<= 1) s += __shfl_xor(s, d, 64);
            rs[mi][r] = 1.f / s;
            int row = wr + mi * 16 + (lane >> 4) * 4 + r;
            #pragma unroll
            for (int ni = 0; ni < 8; ni++) {
                int col = ni * 16 + (lane & 15);
                SA[swzb(row, col >> 3) + (col & 7)] = f2b(p[ni]);
            }
        }
    __syncthreads();   // bar2: all waves done reading K (SB)

    // V transpose into SB (cooperative)
    #pragma unroll
    for (int j = 0; j < 8; j++) {
        bf16x8 col;
        #pragma unroll
        for (int i = 0; i < 8; i++) col[i] = vk[i][j];
        *(bf16x8*)&SB[swzb(n8 * 8 + j, kb)] = col;
    }
    __syncthreads();   // bar3: V staged (P is wave-local)

    f32x4 acc2[2][8];
    #pragma unroll
    for (int mi = 0; mi < 2; mi++)
        #pragma unroll
        for (int ni = 0; ni < 8; ni++) acc2[mi][ni] = (f32x4){0.f, 0.f, 0.f, 0.f};
    mfma32x128(SA, SB, acc2, lane, wr);

    if (!TEPI) {
        // wave-local: bounce scaled output into own SA rows (P dead), store
        #pragma unroll
        for (int mi = 0; mi < 2; mi++)
            #pragma unroll
            for (int r = 0; r < 4; r++) {
                int row = wr + mi * 16 + (lane >> 4) * 4 + r;
                float rinv = rs[mi][r];
                #pragma unroll
                for (int ni = 0; ni < 8; ni++) {
                    int col = ni * 16 + (lane & 15);
                    SA[swzb(row, col >> 3) + (col & 7)] = f2b(acc2[mi][ni][r] * rinv);
                }
            }
        #pragma unroll
        for (int i = 0; i < 8; i++) {
            int idx = lane + i * 64;
            int row = wr + (idx >> 4), ch = idx & 15;
            *(bf16x8*)(Ob + (long long)row * 16384 + ch * 8) =
                *(const bf16x8*)&SA[swzb(row, ch)];
        }
    } else {
        __syncthreads();   // bar4: all done reading SB (V)
        #pragma unroll
        for (int mi = 0; mi < 2; mi++)
            #pragma unroll
            for (int r = 0; r < 4; r++) {
                int row = wr + mi * 16 + (lane >> 4) * 4 + r;
                float rinv = rs[mi][r];
                #pragma unroll
                for (int ni = 0; ni < 8; ni++) {
                    int col = ni * 16 + (lane & 15);
                    SB[swzb(col, row >> 3) + (row & 7)] = f2b(acc2[mi][ni][r] * rinv);
                }
            }
        __syncthreads();   // bar5
        #pragma unroll
        for (int i = 0; i < 8; i++) {
            int idx = t + i * 256;
            int row = idx >> 4, ch = idx & 15;
            *(bf16x8*)(Ob + (long long)row * 16384 + ch * 8) =
                *(const bf16x8*)&SB[swzb(row, ch)];
        }
    }
}

extern "C" void kernel_launch(void* const* d_in, const int* in_sizes, int n_in,
                              void* d_out, int out_size, void* d_ws, size_t ws_size,
                              hipStream_t stream) {
    const float* x   = (const float*)d_in[0];
    const float* Wr  = (const float*)d_in[1];
    const float* br  = (const float*)d_in[2];
    const float* Wqw = (const float*)d_in[3];
    const float* bqw = (const float*)d_in[4];
    const float* Wkw = (const float*)d_in[5];
    const float* bkw = (const float*)d_in[6];
    const float* Wvw = (const float*)d_in[7];
    const float* bvw = (const float*)d_in[8];
    const float* Wqh = (const float*)d_in[9];
    const float* bqh = (const float*)d_in[10];
    const float* Wkh = (const float*)d_in[11];
    const float* bkh = (const float*)d_in[12];
    const float* Wvh = (const float*)d_in[13];
    const float* bvh = (const float*)d_in[14];
    const float* Wo  = (const float*)d_in[15];
    const float* bo  = (const float*)d_in[16];
    float* out = (float*)d_out;
    (void)in_sizes; (void)n_in; (void)out_size; (void)ws_size;

    // bf16 workspace, U = 8*128^3 elems (33.5MB). 4U tensors + weight images.
    // s0: rsz -> T1 -> T2 ; s1: q1 -> q2 ; s2: k1 -> k2 ; s3: v1 -> v2.
    const long long U = 16777216LL;
    short* wsp = (short*)d_ws;
    short* s0 = wsp;
    short* s1 = wsp + U;
    short* s2 = wsp + 2 * U;
    short* s3 = wsp + 3 * U;
    short* wb = wsp + 4 * U;
    short* wWr  = wb;
    short* wWqw = wb + 32768;
    short* wWkw = wb + 49152;
    short* wWvw = wb + 65536;
    short* wWqh = wb + 81920;
    short* wWkh = wb + 98304;
    short* wWvh = wb + 114688;
    short* wWo  = wb + 131072;

    dim3 blk(256);

    wprep<<<dim3(16, 8), blk, 0, stream>>>(Wr, Wqw, Wkw, Wvw, Wqh, Wkh, Wvh, Wo, wb);

    // P1: rsz[b][p][h][w] <- x, per (b,h-chunk); B fp32 n-fast, K=256
    gemm_p1<<<dim3(128, 1, 8), blk, 0, stream>>>(
        wWr, br, x, 4194304LL, 128LL, 16384LL,
        s0, 2097152LL, 128LL, 16384LL);

    // P2: q1,k1,v1[b][o][p][w], per (b,p,my); B = rsz bf16 n-fast, NW=3
    gemmw64<3, 1, false><<<dim3(128, 2, 8), blk, 0, stream>>>(
        wWqw, wWkw, wWvw, bqw, bkw, bvw,
        s0, 2097152LL, 16384LL, 128LL,
        s1, s2, s3, nullptr, 2097152LL, 128LL, 16384LL);

    // P3: width attention -> T1[b][p][o][w] (into s0; rsz dead)
    attnk<false><<<dim3(128, 1, 8), blk, 0, stream>>>(s1, s2, s3, s0);

    // P4: q2,k2,v2, per (b,c,my); B = T1 k-fast, NW=3
    gemmw64<3, 0, false><<<dim3(128, 2, 8), blk, 0, stream>>>(
        wWqh, wWkh, wWvh, bqh, bkh, bvh,
        s0, 2097152LL, 16384LL, 128LL,
        s1, s2, s3, nullptr, 2097152LL, 128LL, 16384LL);

    // P5: height attention -> T2[b][h][o2][c] (into s0; T1 dead)
    attnk<true><<<dim3(128, 1, 8), blk, 0, stream>>>(s1, s2, s3, s0);

    // P6: out[b][co][h][o2] fp32, per (b,h,my4); B = T2 k-fast
    gemmw64<1, 0, true><<<dim3(128, 4, 8), blk, 0, stream>>>(
        wWo, nullptr, nullptr, bo, nullptr, nullptr,
        s0, 2097152LL, 16384LL, 128LL,
        nullptr, nullptr, nullptr, out, 4194304LL, 128LL, 16384LL);
}